// Round 5
// baseline (335.257 us; speedup 1.0000x reference)
//
#include <hip/hip_runtime.h>
#include <stdint.h>
#include <stddef.h>

#define Tq 2048
#define DM 1024

typedef unsigned short u16;
typedef __bf16 bf16x8 __attribute__((ext_vector_type(8)));
typedef float f32x4 __attribute__((ext_vector_type(4)));
typedef unsigned short u16x8 __attribute__((ext_vector_type(8)));
typedef unsigned short u16x4 __attribute__((ext_vector_type(4)));

__device__ __forceinline__ float bf2f(u16 h) {
    union { unsigned int u; float f; } c; c.u = ((unsigned int)h) << 16; return c.f;
}
__device__ __forceinline__ u16 f2bf(float f) {
    union { float f; unsigned int u; } c; c.f = f;
    unsigned int u = c.u;
    return (u16)((u + 0x7fffu + ((u >> 16) & 1u)) >> 16);  // RNE
}

// async global->LDS, 16B per lane; lds base wave-uniform (HW adds lane*16)
#define GLD(gp, lp) __builtin_amdgcn_global_load_lds(                                  \
        (const __attribute__((address_space(1))) void*)(gp),                           \
        (__attribute__((address_space(3))) void*)(lp), 16, 0, 0)

// ---------------------------------------------------------------------------
// Format sniff (round-3 proven).
// ---------------------------------------------------------------------------
__device__ __forceinline__ int sniff_fp32(const u16* xs) {
    const int lane = threadIdx.x & 63;
    const u16 u = xs[lane];
    const int e = (u >> 7) & 0xFF;
    unsigned long long m = __ballot(e >= 160);
    return __popcll(m) >= 4;
}

__device__ __forceinline__ void cvt_body(const void* src, u16* dst, int i0, int fmt) {
    if (fmt) {
        const float* s = (const float*)src;
        float4 a = *(const float4*)(s + i0);
        float4 b = *(const float4*)(s + i0 + 4);
        u16x8 o;
        o[0] = f2bf(a.x); o[1] = f2bf(a.y); o[2] = f2bf(a.z); o[3] = f2bf(a.w);
        o[4] = f2bf(b.x); o[5] = f2bf(b.y); o[6] = f2bf(b.z); o[7] = f2bf(b.w);
        *(u16x8*)(dst + i0) = o;
    } else {
        *(u16x8*)(dst + i0) = *(const u16x8*)((const u16*)src + i0);
    }
}

__global__ void cvt_tensor(const void* __restrict__ src, u16* __restrict__ dst, int n,
                           const u16* __restrict__ xs, int* flag, int writeflag) {
    const int fmt = sniff_fp32(xs);
    if (writeflag && blockIdx.x == 0 && threadIdx.x == 0) *flag = fmt;
    const int i0 = (blockIdx.x * 256 + threadIdx.x) * 8;
    if (i0 >= n) return;
    cvt_body(src, dst, i0, fmt);
}

// All four weights + all four biases in one launch: grid (512, 4).
__global__ void cvt_w4b(const void* s0, const void* s1, const void* s2, const void* s3,
                        const void* t0, const void* t1, const void* t2, const void* t3,
                        u16* __restrict__ dstW, float* __restrict__ dstB,
                        const u16* __restrict__ xs) {
    const int fmt = sniff_fp32(xs);
    const int wsel = blockIdx.y;
    const void* s = (wsel == 0) ? s0 : (wsel == 1) ? s1 : (wsel == 2) ? s2 : s3;
    u16* d = dstW + (size_t)wsel * (DM * DM);
    const int i0 = (blockIdx.x * 256 + threadIdx.x) * 8;
    cvt_body(s, d, i0, fmt);
    if (blockIdx.x == 0) {                         // bias wsel piggybacked
        const void* bs = (wsel == 0) ? t0 : (wsel == 1) ? t1 : (wsel == 2) ? t2 : t3;
        float* db = dstB + (size_t)wsel * DM;
        const int j0 = threadIdx.x * 4;
        if (fmt) {
            *(float4*)(db + j0) = *(const float4*)((const float*)bs + j0);
        } else {
            const u16* ss = (const u16*)bs;
            db[j0+0] = bf2f(ss[j0+0]); db[j0+1] = bf2f(ss[j0+1]);
            db[j0+2] = bf2f(ss[j0+2]); db[j0+3] = bf2f(ss[j0+3]);
        }
    }
}

// ---------------------------------------------------------------------------
// GEMM, m97 structure. Round 4: in mode 0, the V projection (which == 2) is
// stored DIRECTLY transposed as (B,H,64,T) — eliminates vtrans (proven).
// ---------------------------------------------------------------------------
__global__ __launch_bounds__(256, 2) void gemm_bt(
    const u16* __restrict__ A,
    const u16* __restrict__ W0, const u16* __restrict__ W1, const u16* __restrict__ W2,
    const float* __restrict__ b0, const float* __restrict__ b1, const float* __restrict__ b2,
    u16* o0, u16* o1, u16* o2,
    const int* __restrict__ flag, int mode)
{
    __shared__ u16 Alds[128 * 64];
    __shared__ u16 Blds[128 * 64];

    const int K = DM;
    const int i = blockIdx.x;
    const int j = blockIdx.y;
    const int which = (mode == 0) ? (j >> 3) : 0;
    const u16* W      = (which == 0) ? W0 : (which == 1) ? W1 : W2;
    const float* bias = (which == 0) ? b0 : (which == 1) ? b1 : b2;
    u16* out          = (which == 0) ? o0 : (which == 1) ? o1 : o2;
    const int jn = (mode == 0) ? (j & 7) : j;
    const int m0 = i * 128, n0 = jn * 128;
    const int ofmt = (mode == 1) ? *flag : 0;

    const int tid = threadIdx.x;
    const int w = tid >> 6, lane = tid & 63;
    const int l4 = lane & 15, quad = lane >> 4;
    const int wrow = w >> 1, wcol = w & 1;

    f32x4 acc[4][4] = {};

    for (int k0 = 0; k0 < K; k0 += 64) {
        __syncthreads();
#pragma unroll
        for (int c = 0; c < 4; ++c) {
            const int u   = w * 1024 + c * 4096;
            const int off = u + lane * 16;
            const int row = off >> 7;
            const int col = (off & 127) >> 1;
            GLD(A + (size_t)(m0 + row) * K + k0 + col, (char*)Alds + u);
            GLD(W + (size_t)(n0 + row) * K + k0 + col, (char*)Blds + u);
        }
        __syncthreads();
#pragma unroll
        for (int c = 0; c < 2; ++c) {
            bf16x8 af[4], bfr[4];
#pragma unroll
            for (int r = 0; r < 4; ++r)
                af[r] = *(const bf16x8*)&Alds[(wrow*64 + r*16 + l4) * 64 + c*32 + quad*8];
#pragma unroll
            for (int n = 0; n < 4; ++n)
                bfr[n] = *(const bf16x8*)&Blds[(wcol*64 + n*16 + l4) * 64 + c*32 + quad*8];
#pragma unroll
            for (int r = 0; r < 4; ++r)
#pragma unroll
                for (int n = 0; n < 4; ++n)
                    acc[r][n] = __builtin_amdgcn_mfma_f32_16x16x32_bf16(af[r], bfr[n], acc[r][n], 0, 0, 0);
        }
    }

#pragma unroll
    for (int n = 0; n < 4; ++n) {
        const int col = n0 + wcol*64 + n*16 + l4;
        const float bv = bias[col];
#pragma unroll
        for (int r = 0; r < 4; ++r) {
            const int mb = m0 + wrow*64 + r*16 + quad*4;
            if (mode == 0 && which == 2) {
                // V -> (B,H,64,T) transposed store.
                const int b = mb >> 11, t0 = mb & 2047;
                const int h = col >> 6, d = col & 63;
                u16x4 pk;
#pragma unroll
                for (int reg = 0; reg < 4; ++reg) pk[reg] = f2bf(acc[r][n][reg] + bv);
                *(u16x4*)&out[((size_t)(b*16 + h) * 64 + d) * 2048 + t0] = pk;
            } else {
#pragma unroll
                for (int reg = 0; reg < 4; ++reg) {
                    const int m = mb + reg;
                    const float val = acc[r][n][reg] + bv;
                    if (mode == 0) {
                        const int b = m >> 11, t = m & 2047;
                        const int h = col >> 6, d = col & 63;
                        out[(size_t)((b*16 + h) * 2048 + t) * 64 + d] = f2bf(val);
                    } else if (ofmt) {
                        ((float*)out)[(size_t)m * DM + col] = val;
                    } else {
                        out[(size_t)m * DM + col] = f2bf(val);
                    }
                }
            }
        }
    }
}

// ---------------------------------------------------------------------------
// Flash attention v5 — round-4 inner structure EXACTLY (hoisted kf/vf,
// QK-then-PV phases, 2 barriers/kt, diag-only masking), but 2 q-tiles per
// block {nb, 31-nb} (nb=0..15) instead of 4:
//   * grid (64,16) = 1024 blocks AND Pl[2] -> LDS 36.9 KB => 4 blocks/CU
//     (round-3 lesson: LDS diet without grid growth buys nothing; this has
//     both). 16 waves/CU vs 8 — attacks the VALU-latency limit (VALUBusy
//     49% @ 19% occupancy).
//   * G=2 sheds ~56 VGPR of per-group state -> fits the 128-reg budget of
//     __launch_bounds__(256,4). Tripwire: WRITE_SIZE must stay ~16.4 MB;
//     growth = spill => revert to (256,3).
//   * Work per block constant: (nb+1) + (32-nb) = 33 tiles.
//   * Accepted cost: kf/vf reuse 4x->2x (bank conflicts ~2x, absorbed by
//     doubled occupancy).
// ---------------------------------------------------------------------------
#define LSTR 72

__global__ __launch_bounds__(256, 4) void attn4(
    const u16* __restrict__ Qb, const u16* __restrict__ Kb, const u16* __restrict__ VT,
    const unsigned char* __restrict__ pad,
    u16* __restrict__ Y)
{
    __shared__ u16 Klds[64 * LSTR];
    __shared__ u16 Vtl [64 * LSTR];
    __shared__ u16 Pl  [2][64 * LSTR];
    __shared__ unsigned char padl[64];

    const int nb = blockIdx.y;           // 0..15
    const int bh = blockIdx.x;           // 0..63 -> XCD = bh % 8
    const int b = bh >> 4, h = bh & 15;
    const u16* Qp  = Qb + (size_t)bh * (Tq * 64);
    const u16* Kp  = Kb + (size_t)bh * (Tq * 64);
    const u16* VTp = VT + (size_t)bh * (64 * Tq);

    const int tid = threadIdx.x;
    const int w = tid >> 6, lane = tid & 63;
    const int l4 = lane & 15, quad = lane >> 4;

    const int qt[2] = { nb, 31 - nb };   // ascending; covers 0..31 over nb

    bf16x8 qf[2][2];
#pragma unroll
    for (int g = 0; g < 2; ++g) {
        const u16* r = Qp + (size_t)(qt[g] * 64 + w * 16 + l4) * 64 + quad * 8;
        qf[g][0] = *(const bf16x8*)r;
        qf[g][1] = *(const bf16x8*)(r + 32);
    }

    f32x4 o[2][4] = {};
    float l[2][4] = {};

    const int srow = tid >> 2;
    const int sc   = (tid & 3) * 16;

    u16x8 kr0, kr1, vr0, vr1; unsigned char pr = 0;
    {
        const u16* kg = Kp + (size_t)srow * 64 + sc;
        kr0 = *(const u16x8*)kg; kr1 = *(const u16x8*)(kg + 8);
        const u16* vg = VTp + (size_t)srow * Tq + sc;
        vr0 = *(const u16x8*)vg; vr1 = *(const u16x8*)(vg + 8);
        if (tid < 64) pr = pad[(size_t)b * Tq + tid];
    }

    const float SC = 0.18033688011112042f;   // log2(e)/sqrt(64)
    const int ktmax = qt[1];

    for (int kt = 0; kt <= ktmax; ++kt) {
        const int k0 = kt * 64;
        __syncthreads();                       // prev PV done with Klds/Vtl
        *(u16x8*)&Klds[srow * LSTR + sc]     = kr0;
        *(u16x8*)&Klds[srow * LSTR + sc + 8] = kr1;
        *(u16x8*)&Vtl [srow * LSTR + sc]     = vr0;
        *(u16x8*)&Vtl [srow * LSTR + sc + 8] = vr1;
        if (tid < 64) padl[tid] = pr;
        __syncthreads();                       // staging visible
        if (kt < ktmax) {                      // prefetch next tile into regs
            const u16* kg = Kp + (size_t)(k0 + 64 + srow) * 64 + sc;
            kr0 = *(const u16x8*)kg; kr1 = *(const u16x8*)(kg + 8);
            const u16* vg = VTp + (size_t)srow * Tq + k0 + 64 + sc;
            vr0 = *(const u16x8*)vg; vr1 = *(const u16x8*)(vg + 8);
            if (tid < 64) pr = pad[(size_t)b * Tq + k0 + 64 + tid];
        }

        const bool anypad = __any((int)(padl[lane] != 0));   // wave-uniform

        // ---- QK^T for active groups; kf shared across groups ----
        bf16x8 kf[2][4];
#pragma unroll
        for (int c = 0; c < 2; ++c)
#pragma unroll
            for (int n = 0; n < 4; ++n)
                kf[c][n] = *(const bf16x8*)&Klds[(n * 16 + l4) * LSTR + c * 32 + quad * 8];

#pragma unroll
        for (int g = 0; g < 2; ++g) {
            if (kt > qt[g]) continue;          // wave-uniform branch
            f32x4 sacc[4] = {};
            __builtin_amdgcn_s_setprio(1);
#pragma unroll
            for (int c = 0; c < 2; ++c)
#pragma unroll
                for (int n = 0; n < 4; ++n)
                    sacc[n] = __builtin_amdgcn_mfma_f32_16x16x32_bf16(qf[g][c], kf[c][n], sacc[n], 0, 0, 0);
            __builtin_amdgcn_s_setprio(0);
            u16* Pg = &Pl[g][0];
            if (kt == qt[g] || anypad) {       // diagonal tile or padding
                bool pm[4];
#pragma unroll
                for (int n = 0; n < 4; ++n) pm[n] = (padl[n * 16 + l4] != 0);
                const int qr = qt[g] * 64 + w * 16 + quad * 4;
#pragma unroll
                for (int r = 0; r < 4; ++r) {
                    float rs = 0.f;
#pragma unroll
                    for (int n = 0; n < 4; ++n) {
                        const int kgi = k0 + n * 16 + l4;
                        const bool msk = (kgi > qr + r) || pm[n];
                        const float p = msk ? 0.0f : exp2f(sacc[n][r] * SC);
                        rs += p;
                        *(__bf16*)&Pg[(w * 16 + quad * 4 + r) * LSTR + n * 16 + l4] = (__bf16)p;
                    }
                    l[g][r] += rs;
                }
            } else {                            // interior, no padding
#pragma unroll
                for (int r = 0; r < 4; ++r) {
                    float rs = 0.f;
#pragma unroll
                    for (int n = 0; n < 4; ++n) {
                        const float p = exp2f(sacc[n][r] * SC);
                        rs += p;
                        *(__bf16*)&Pg[(w * 16 + quad * 4 + r) * LSTR + n * 16 + l4] = (__bf16)p;
                    }
                    l[g][r] += rs;
                }
            }
        }

        // ---- PV for active groups; vf shared across groups ----
        // No barrier needed: P is wave-private.
        bf16x8 vf[2][4];
#pragma unroll
        for (int c = 0; c < 2; ++c)
#pragma unroll
            for (int t = 0; t < 4; ++t)
                vf[c][t] = *(const bf16x8*)&Vtl[(t * 16 + l4) * LSTR + c * 32 + quad * 8];

#pragma unroll
        for (int g = 0; g < 2; ++g) {
            if (kt > qt[g]) continue;
            __builtin_amdgcn_s_setprio(1);
#pragma unroll
            for (int c = 0; c < 2; ++c) {
                bf16x8 pf = *(const bf16x8*)&Pl[g][(w * 16 + l4) * LSTR + c * 32 + quad * 8];
#pragma unroll
                for (int t = 0; t < 4; ++t)
                    o[g][t] = __builtin_amdgcn_mfma_f32_16x16x32_bf16(pf, vf[c][t], o[g][t], 0, 0, 0);
            }
            __builtin_amdgcn_s_setprio(0);
        }
    }

#pragma unroll
    for (int g = 0; g < 2; ++g)
#pragma unroll
        for (int r = 0; r < 4; ++r)
#pragma unroll
            for (int s = 1; s < 16; s <<= 1)
                l[g][r] += __shfl_xor(l[g][r], s);

#pragma unroll
    for (int g = 0; g < 2; ++g)
#pragma unroll
        for (int r = 0; r < 4; ++r) {
            const float inv = 1.0f / l[g][r];
            u16* y = Y + (size_t)(b * Tq + (qt[g] * 64 + w * 16 + quad * 4 + r)) * DM + h * 64;
#pragma unroll
            for (int t = 0; t < 4; ++t)
                *(__bf16*)&y[t * 16 + l4] = (__bf16)(o[g][t][r] * inv);
        }
}

// ---------------------------------------------------------------------------
extern "C" void kernel_launch(void* const* d_in, const int* in_sizes, int n_in,
                              void* d_out, int out_size, void* d_ws, size_t ws_size,
                              hipStream_t stream) {
    const void* x  = d_in[0];
    const unsigned char* pad = (const unsigned char*)d_in[1];
    const void* Wq = d_in[2];
    const void* bq = d_in[3];
    const void* Wk = d_in[4];
    const void* bk = d_in[5];
    const void* Wv = d_in[6];
    const void* bv = d_in[7];
    const void* Wo = d_in[8];
    const void* bo = d_in[9];
    const u16* xs = (const u16*)x;

    const size_t NEL = (size_t)8192 * 1024;
    const size_t WEL = (size_t)1024 * 1024;

    int* flag   = (int*)d_ws;
    u16* base16 = (u16*)((char*)d_ws + 256);
    u16* xc     = base16;                          // canonical x; reused as Yb
    u16* Wc     = base16 + NEL;                    // Wq,Wk,Wv,Wo
    float* bf_  = (float*)(base16 + NEL + 4*WEL);  // 4 x 1024 fp32 biases
    u16* Qb     = (u16*)(bf_ + 4096);
    u16* Kb     = Qb + NEL;
    u16* VT     = Kb + NEL;                        // (B,H,64,T) — written by gemm0
    u16* Yb     = xc;

    cvt_tensor<<<dim3((int)(NEL/2048)), 256, 0, stream>>>(x, xc, (int)NEL, xs, flag, 1);
    cvt_w4b<<<dim3(512, 4), 256, 0, stream>>>(Wq, Wk, Wv, Wo, bq, bk, bv, bo, Wc, bf_, xs);

    gemm_bt<<<dim3(64, 24), 256, 0, stream>>>(xc, Wc, Wc + WEL, Wc + 2*WEL,
                                              bf_, bf_ + 1024, bf_ + 2048,
                                              Qb, Kb, VT, flag, 0);
    attn4<<<dim3(64, 16), 256, 0, stream>>>(Qb, Kb, VT, pad, Yb);
    gemm_bt<<<dim3(64, 8), 256, 0, stream>>>(Yb, Wc + 3*WEL, Wc + 3*WEL, Wc + 3*WEL,
                                             bf_ + 3072, bf_ + 3072, bf_ + 3072,
                                             (u16*)d_out, nullptr, nullptr, flag, 1);
}

// Round 6
// 278.105 us; speedup vs baseline: 1.2055x; 1.2055x over previous
//
#include <hip/hip_runtime.h>
#include <stdint.h>
#include <stddef.h>

#define Tq 2048
#define DM 1024

typedef unsigned short u16;
typedef __bf16 bf16x8 __attribute__((ext_vector_type(8)));
typedef float f32x4 __attribute__((ext_vector_type(4)));
typedef unsigned short u16x8 __attribute__((ext_vector_type(8)));
typedef unsigned short u16x4 __attribute__((ext_vector_type(4)));

__device__ __forceinline__ float bf2f(u16 h) {
    union { unsigned int u; float f; } c; c.u = ((unsigned int)h) << 16; return c.f;
}
__device__ __forceinline__ u16 f2bf(float f) {
    union { float f; unsigned int u; } c; c.f = f;
    unsigned int u = c.u;
    return (u16)((u + 0x7fffu + ((u >> 16) & 1u)) >> 16);  // RNE
}

// async global->LDS, 16B per lane; lds base wave-uniform (HW adds lane*16)
#define GLD(gp, lp) __builtin_amdgcn_global_load_lds(                                  \
        (const __attribute__((address_space(1))) void*)(gp),                           \
        (__attribute__((address_space(3))) void*)(lp), 16, 0, 0)

// ---------------------------------------------------------------------------
// Format sniff (round-3 proven).
// ---------------------------------------------------------------------------
__device__ __forceinline__ int sniff_fp32(const u16* xs) {
    const int lane = threadIdx.x & 63;
    const u16 u = xs[lane];
    const int e = (u >> 7) & 0xFF;
    unsigned long long m = __ballot(e >= 160);
    return __popcll(m) >= 4;
}

__device__ __forceinline__ void cvt_body(const void* src, u16* dst, int i0, int fmt) {
    if (fmt) {
        const float* s = (const float*)src;
        float4 a = *(const float4*)(s + i0);
        float4 b = *(const float4*)(s + i0 + 4);
        u16x8 o;
        o[0] = f2bf(a.x); o[1] = f2bf(a.y); o[2] = f2bf(a.z); o[3] = f2bf(a.w);
        o[4] = f2bf(b.x); o[5] = f2bf(b.y); o[6] = f2bf(b.z); o[7] = f2bf(b.w);
        *(u16x8*)(dst + i0) = o;
    } else {
        *(u16x8*)(dst + i0) = *(const u16x8*)((const u16*)src + i0);
    }
}

// ---------------------------------------------------------------------------
// Fused canonicalization: x (blocks 0..4095) + 4 weights/biases (4096..6143).
// One launch instead of two (round-6).
// ---------------------------------------------------------------------------
__global__ void cvt_all(const void* __restrict__ x,
                        const void* s0, const void* s1, const void* s2, const void* s3,
                        const void* t0, const void* t1, const void* t2, const void* t3,
                        u16* __restrict__ xc, u16* __restrict__ dstW, float* __restrict__ dstB,
                        const u16* __restrict__ xs, int* flag) {
    const int fmt = sniff_fp32(xs);
    int bx = blockIdx.x;
    if (bx < 4096) {
        if (bx == 0 && threadIdx.x == 0) *flag = fmt;
        const int i0 = (bx * 256 + threadIdx.x) * 8;
        cvt_body(x, xc, i0, fmt);
    } else {
        bx -= 4096;
        const int wsel = bx >> 9;          // 0..3
        const int bi   = bx & 511;
        const void* s = (wsel == 0) ? s0 : (wsel == 1) ? s1 : (wsel == 2) ? s2 : s3;
        u16* d = dstW + (size_t)wsel * (DM * DM);
        const int i0 = (bi * 256 + threadIdx.x) * 8;
        cvt_body(s, d, i0, fmt);
        if (bi == 0) {                     // bias piggybacked
            const void* bs = (wsel == 0) ? t0 : (wsel == 1) ? t1 : (wsel == 2) ? t2 : t3;
            float* db = dstB + (size_t)wsel * DM;
            const int j0 = threadIdx.x * 4;
            if (fmt) {
                *(float4*)(db + j0) = *(const float4*)((const float*)bs + j0);
            } else {
                const u16* ss = (const u16*)bs;
                db[j0+0] = bf2f(ss[j0+0]); db[j0+1] = bf2f(ss[j0+1]);
                db[j0+2] = bf2f(ss[j0+2]); db[j0+3] = bf2f(ss[j0+3]);
            }
        }
    }
}

// ---------------------------------------------------------------------------
// GEMM, m97 structure. Round 4: in mode 0, the V projection (which == 2) is
// stored DIRECTLY transposed as (B,H,64,T) — eliminates vtrans (proven).
// ---------------------------------------------------------------------------
__global__ __launch_bounds__(256, 2) void gemm_bt(
    const u16* __restrict__ A,
    const u16* __restrict__ W0, const u16* __restrict__ W1, const u16* __restrict__ W2,
    const float* __restrict__ b0, const float* __restrict__ b1, const float* __restrict__ b2,
    u16* o0, u16* o1, u16* o2,
    const int* __restrict__ flag, int mode)
{
    __shared__ u16 Alds[128 * 64];
    __shared__ u16 Blds[128 * 64];

    const int K = DM;
    const int i = blockIdx.x;
    const int j = blockIdx.y;
    const int which = (mode == 0) ? (j >> 3) : 0;
    const u16* W      = (which == 0) ? W0 : (which == 1) ? W1 : W2;
    const float* bias = (which == 0) ? b0 : (which == 1) ? b1 : b2;
    u16* out          = (which == 0) ? o0 : (which == 1) ? o1 : o2;
    const int jn = (mode == 0) ? (j & 7) : j;
    const int m0 = i * 128, n0 = jn * 128;
    const int ofmt = (mode == 1) ? *flag : 0;

    const int tid = threadIdx.x;
    const int w = tid >> 6, lane = tid & 63;
    const int l4 = lane & 15, quad = lane >> 4;
    const int wrow = w >> 1, wcol = w & 1;

    f32x4 acc[4][4] = {};

    for (int k0 = 0; k0 < K; k0 += 64) {
        __syncthreads();
#pragma unroll
        for (int c = 0; c < 4; ++c) {
            const int u   = w * 1024 + c * 4096;
            const int off = u + lane * 16;
            const int row = off >> 7;
            const int col = (off & 127) >> 1;
            GLD(A + (size_t)(m0 + row) * K + k0 + col, (char*)Alds + u);
            GLD(W + (size_t)(n0 + row) * K + k0 + col, (char*)Blds + u);
        }
        __syncthreads();
#pragma unroll
        for (int c = 0; c < 2; ++c) {
            bf16x8 af[4], bfr[4];
#pragma unroll
            for (int r = 0; r < 4; ++r)
                af[r] = *(const bf16x8*)&Alds[(wrow*64 + r*16 + l4) * 64 + c*32 + quad*8];
#pragma unroll
            for (int n = 0; n < 4; ++n)
                bfr[n] = *(const bf16x8*)&Blds[(wcol*64 + n*16 + l4) * 64 + c*32 + quad*8];
#pragma unroll
            for (int r = 0; r < 4; ++r)
#pragma unroll
                for (int n = 0; n < 4; ++n)
                    acc[r][n] = __builtin_amdgcn_mfma_f32_16x16x32_bf16(af[r], bfr[n], acc[r][n], 0, 0, 0);
        }
    }

#pragma unroll
    for (int n = 0; n < 4; ++n) {
        const int col = n0 + wcol*64 + n*16 + l4;
        const float bv = bias[col];
#pragma unroll
        for (int r = 0; r < 4; ++r) {
            const int mb = m0 + wrow*64 + r*16 + quad*4;
            if (mode == 0 && which == 2) {
                // V -> (B,H,64,T) transposed store.
                const int b = mb >> 11, t0 = mb & 2047;
                const int h = col >> 6, d = col & 63;
                u16x4 pk;
#pragma unroll
                for (int reg = 0; reg < 4; ++reg) pk[reg] = f2bf(acc[r][n][reg] + bv);
                *(u16x4*)&out[((size_t)(b*16 + h) * 64 + d) * 2048 + t0] = pk;
            } else {
#pragma unroll
                for (int reg = 0; reg < 4; ++reg) {
                    const int m = mb + reg;
                    const float val = acc[r][n][reg] + bv;
                    if (mode == 0) {
                        const int b = m >> 11, t = m & 2047;
                        const int h = col >> 6, d = col & 63;
                        out[(size_t)((b*16 + h) * 2048 + t) * 64 + d] = f2bf(val);
                    } else if (ofmt) {
                        ((float*)out)[(size_t)m * DM + col] = val;
                    } else {
                        out[(size_t)m * DM + col] = f2bf(val);
                    }
                }
            }
        }
    }
}

// ---------------------------------------------------------------------------
// Flash attention v6 — round-4 inner structure EXACTLY (G=4 q-tiles
// {n,n+8,23-n,31-n}, hoisted kf/vf, Pl[4], diag-only masking,
// __launch_bounds__(256,2) for the 256-VGPR budget), with ONE change:
// K/V/pad double-buffered in LDS -> ONE barrier per kt instead of two.
//   iter kt: barrier(buf[cur] visible + prev reads drained) ->
//            prefetch kt+1 to regs -> compute from buf[cur] ->
//            ds_write regs -> buf[cur^1]  (T14 issue-early/write-late).
// Race-free: writes always target the opposite buffer; __syncthreads drains
// lgkm, so buf[cur] is never overwritten before all its readers passed the
// barrier. LDS 73.9 KB -> still 2 blocks/CU (occupancy pinned there anyway;
// rounds 3+5 proved the VGPR budget forbids more). Staging regs now live
// through compute: ~140 VGPR, well under 256.
// Round-5 lesson: do NOT tighten launch bounds — (256,4) clamps to 64 VGPR
// and spills ~300 MB of scratch.
// ---------------------------------------------------------------------------
#define LSTR 72

__global__ __launch_bounds__(256, 2) void attn4(
    const u16* __restrict__ Qb, const u16* __restrict__ Kb, const u16* __restrict__ VT,
    const unsigned char* __restrict__ pad,
    u16* __restrict__ Y)
{
    __shared__ u16 Klds[2][64 * LSTR];
    __shared__ u16 Vtl [2][64 * LSTR];
    __shared__ u16 Pl  [4][64 * LSTR];
    __shared__ unsigned char padl[2][64];

    const int nb = blockIdx.y;           // 0..7
    const int bh = blockIdx.x;           // 0..63 -> XCD = bh % 8
    const int b = bh >> 4, h = bh & 15;
    const u16* Qp  = Qb + (size_t)bh * (Tq * 64);
    const u16* Kp  = Kb + (size_t)bh * (Tq * 64);
    const u16* VTp = VT + (size_t)bh * (64 * Tq);

    const int tid = threadIdx.x;
    const int w = tid >> 6, lane = tid & 63;
    const int l4 = lane & 15, quad = lane >> 4;

    const int qt[4] = { nb, nb + 8, 23 - nb, 31 - nb };   // ascending

    bf16x8 qf[4][2];
#pragma unroll
    for (int g = 0; g < 4; ++g) {
        const u16* r = Qp + (size_t)(qt[g] * 64 + w * 16 + l4) * 64 + quad * 8;
        qf[g][0] = *(const bf16x8*)r;
        qf[g][1] = *(const bf16x8*)(r + 32);
    }

    f32x4 o[4][4] = {};
    float l[4][4] = {};

    const int srow = tid >> 2;
    const int sc   = (tid & 3) * 16;

    u16x8 kr0, kr1, vr0, vr1; unsigned char pr = 0;
    {   // tile 0 -> regs
        const u16* kg = Kp + (size_t)srow * 64 + sc;
        kr0 = *(const u16x8*)kg; kr1 = *(const u16x8*)(kg + 8);
        const u16* vg = VTp + (size_t)srow * Tq + sc;
        vr0 = *(const u16x8*)vg; vr1 = *(const u16x8*)(vg + 8);
        if (tid < 64) pr = pad[(size_t)b * Tq + tid];
    }
    // prologue: stage tile 0 into buf 0
    *(u16x8*)&Klds[0][srow * LSTR + sc]     = kr0;
    *(u16x8*)&Klds[0][srow * LSTR + sc + 8] = kr1;
    *(u16x8*)&Vtl [0][srow * LSTR + sc]     = vr0;
    *(u16x8*)&Vtl [0][srow * LSTR + sc + 8] = vr1;
    if (tid < 64) padl[0][tid] = pr;

    const float SC = 0.18033688011112042f;   // log2(e)/sqrt(64)
    const int ktmax = qt[3];

    for (int kt = 0; kt <= ktmax; ++kt) {
        const int cur = kt & 1;
        const int k0 = kt * 64;
        __syncthreads();                       // buf[cur] visible; prev reads done
        if (kt < ktmax) {                      // prefetch next tile into regs
            const u16* kg = Kp + (size_t)(k0 + 64 + srow) * 64 + sc;
            kr0 = *(const u16x8*)kg; kr1 = *(const u16x8*)(kg + 8);
            const u16* vg = VTp + (size_t)srow * Tq + k0 + 64 + sc;
            vr0 = *(const u16x8*)vg; vr1 = *(const u16x8*)(vg + 8);
            if (tid < 64) pr = pad[(size_t)b * Tq + k0 + 64 + tid];
        }

        const bool anypad = __any((int)(padl[cur][lane] != 0));   // wave-uniform

        // ---- QK^T for all active groups; kf shared across groups ----
        bf16x8 kf[2][4];
#pragma unroll
        for (int c = 0; c < 2; ++c)
#pragma unroll
            for (int n = 0; n < 4; ++n)
                kf[c][n] = *(const bf16x8*)&Klds[cur][(n * 16 + l4) * LSTR + c * 32 + quad * 8];

#pragma unroll
        for (int g = 0; g < 4; ++g) {
            if (kt > qt[g]) continue;          // wave-uniform branch
            f32x4 sacc[4] = {};
            __builtin_amdgcn_s_setprio(1);
#pragma unroll
            for (int c = 0; c < 2; ++c)
#pragma unroll
                for (int n = 0; n < 4; ++n)
                    sacc[n] = __builtin_amdgcn_mfma_f32_16x16x32_bf16(qf[g][c], kf[c][n], sacc[n], 0, 0, 0);
            __builtin_amdgcn_s_setprio(0);
            u16* Pg = &Pl[g][0];
            if (kt == qt[g] || anypad) {       // diagonal tile or padding
                bool pm[4];
#pragma unroll
                for (int n = 0; n < 4; ++n) pm[n] = (padl[cur][n * 16 + l4] != 0);
                const int qr = qt[g] * 64 + w * 16 + quad * 4;
#pragma unroll
                for (int r = 0; r < 4; ++r) {
                    float rs = 0.f;
#pragma unroll
                    for (int n = 0; n < 4; ++n) {
                        const int kgi = k0 + n * 16 + l4;
                        const bool msk = (kgi > qr + r) || pm[n];
                        const float p = msk ? 0.0f : exp2f(sacc[n][r] * SC);
                        rs += p;
                        *(__bf16*)&Pg[(w * 16 + quad * 4 + r) * LSTR + n * 16 + l4] = (__bf16)p;
                    }
                    l[g][r] += rs;
                }
            } else {                            // interior, no padding
#pragma unroll
                for (int r = 0; r < 4; ++r) {
                    float rs = 0.f;
#pragma unroll
                    for (int n = 0; n < 4; ++n) {
                        const float p = exp2f(sacc[n][r] * SC);
                        rs += p;
                        *(__bf16*)&Pg[(w * 16 + quad * 4 + r) * LSTR + n * 16 + l4] = (__bf16)p;
                    }
                    l[g][r] += rs;
                }
            }
        }

        // ---- PV for all active groups; vf shared across groups ----
        // No barrier needed: P is wave-private.
        bf16x8 vf[2][4];
#pragma unroll
        for (int c = 0; c < 2; ++c)
#pragma unroll
            for (int t = 0; t < 4; ++t)
                vf[c][t] = *(const bf16x8*)&Vtl[cur][(t * 16 + l4) * LSTR + c * 32 + quad * 8];

#pragma unroll
        for (int g = 0; g < 4; ++g) {
            if (kt > qt[g]) continue;
            __builtin_amdgcn_s_setprio(1);
#pragma unroll
            for (int c = 0; c < 2; ++c) {
                bf16x8 pf = *(const bf16x8*)&Pl[g][(w * 16 + l4) * LSTR + c * 32 + quad * 8];
#pragma unroll
                for (int t = 0; t < 4; ++t)
                    o[g][t] = __builtin_amdgcn_mfma_f32_16x16x32_bf16(pf, vf[c][t], o[g][t], 0, 0, 0);
            }
            __builtin_amdgcn_s_setprio(0);
        }

        if (kt < ktmax) {                      // write-late: stage next tile
            *(u16x8*)&Klds[cur ^ 1][srow * LSTR + sc]     = kr0;
            *(u16x8*)&Klds[cur ^ 1][srow * LSTR + sc + 8] = kr1;
            *(u16x8*)&Vtl [cur ^ 1][srow * LSTR + sc]     = vr0;
            *(u16x8*)&Vtl [cur ^ 1][srow * LSTR + sc + 8] = vr1;
            if (tid < 64) padl[cur ^ 1][tid] = pr;
        }
    }

#pragma unroll
    for (int g = 0; g < 4; ++g)
#pragma unroll
        for (int r = 0; r < 4; ++r)
#pragma unroll
            for (int s = 1; s < 16; s <<= 1)
                l[g][r] += __shfl_xor(l[g][r], s);

#pragma unroll
    for (int g = 0; g < 4; ++g)
#pragma unroll
        for (int r = 0; r < 4; ++r) {
            const float inv = 1.0f / l[g][r];
            u16* y = Y + (size_t)(b * Tq + (qt[g] * 64 + w * 16 + quad * 4 + r)) * DM + h * 64;
#pragma unroll
            for (int t = 0; t < 4; ++t)
                *(__bf16*)&y[t * 16 + l4] = (__bf16)(o[g][t][r] * inv);
        }
}

// ---------------------------------------------------------------------------
extern "C" void kernel_launch(void* const* d_in, const int* in_sizes, int n_in,
                              void* d_out, int out_size, void* d_ws, size_t ws_size,
                              hipStream_t stream) {
    const void* x  = d_in[0];
    const unsigned char* pad = (const unsigned char*)d_in[1];
    const void* Wq = d_in[2];
    const void* bq = d_in[3];
    const void* Wk = d_in[4];
    const void* bk = d_in[5];
    const void* Wv = d_in[6];
    const void* bv = d_in[7];
    const void* Wo = d_in[8];
    const void* bo = d_in[9];
    const u16* xs = (const u16*)x;

    const size_t NEL = (size_t)8192 * 1024;
    const size_t WEL = (size_t)1024 * 1024;

    int* flag   = (int*)d_ws;
    u16* base16 = (u16*)((char*)d_ws + 256);
    u16* xc     = base16;                          // canonical x; reused as Yb
    u16* Wc     = base16 + NEL;                    // Wq,Wk,Wv,Wo
    float* bf_  = (float*)(base16 + NEL + 4*WEL);  // 4 x 1024 fp32 biases
    u16* Qb     = (u16*)(bf_ + 4096);
    u16* Kb     = Qb + NEL;
    u16* VT     = Kb + NEL;                        // (B,H,64,T) — written by gemm0
    u16* Yb     = xc;

    cvt_all<<<dim3(6144), 256, 0, stream>>>(x, Wq, Wk, Wv, Wo, bq, bk, bv, bo,
                                            xc, Wc, bf_, xs, flag);

    gemm_bt<<<dim3(64, 24), 256, 0, stream>>>(xc, Wc, Wc + WEL, Wc + 2*WEL,
                                              bf_, bf_ + 1024, bf_ + 2048,
                                              Qb, Kb, VT, flag, 0);
    attn4<<<dim3(64, 8), 256, 0, stream>>>(Qb, Kb, VT, pad, Yb);
    gemm_bt<<<dim3(64, 8), 256, 0, stream>>>(Yb, Wc + 3*WEL, Wc + 3*WEL, Wc + 3*WEL,
                                             bf_ + 3072, bf_ + 3072, bf_ + 3072,
                                             (u16*)d_out, nullptr, nullptr, flag, 1);
}